// Round 18
// baseline (165.740 us; speedup 1.0000x reference)
//
#include <hip/hip_runtime.h>
#include <math.h>
#include <string.h>

#define TPB    512        // threads per block (8 waves)
#define KPT    32         // keys per thread; n = TPB*KPT = 16384
#define SEGC   128        // per-wave segment capacity (8*128*4B = 4 KiB LDS)
#define CAPREG 1024       // tier-A cap: 16 regs/lane * 64 lanes
#define NWAVE  (TPB/64)

typedef float f32x4 __attribute__((ext_vector_type(4)));   // native vec for NT store

// ---------------- boost precompute: boost = f32(exp(f64(1.5f*(0.02f - dc)))) ----
__global__ void boost_kernel(const float* __restrict__ dc, float* __restrict__ boost, int n) {
    int i = blockIdx.x * blockDim.x + threadIdx.x;
    if (i < n) {
        float a = 1.5f * (0.02f - dc[i]);   // exact f32 arithmetic, same as reference
        boost[i] = (float)exp((double)a);   // correctly-rounded f32 exp via f64
    }
}

// monotone float -> uint32 key (no NaNs in input)
__device__ __forceinline__ unsigned fkey(float f) {
    unsigned u = __float_as_uint(f);
    return (u & 0x80000000u) ? ~u : (u | 0x80000000u);
}

// wave-wide sums of per-lane counts via bit-plane ballots; uniform result.
__device__ __forceinline__ int wave_sum6(int c) {
    int t;
    t  = (int)__popcll(__ballot(c & 1));
    t += (int)__popcll(__ballot(c & 2))  << 1;
    t += (int)__popcll(__ballot(c & 4))  << 2;
    t += (int)__popcll(__ballot(c & 8))  << 3;
    t += (int)__popcll(__ballot(c & 16)) << 4;
    t += (int)__popcll(__ballot(c & 32)) << 5;
    return t;
}
__device__ __forceinline__ int wave_sum5(int c) {   // counts <= 16 per lane
    int t;
    t  = (int)__popcll(__ballot(c & 1));
    t += (int)__popcll(__ballot(c & 2))  << 1;
    t += (int)__popcll(__ballot(c & 4))  << 2;
    t += (int)__popcll(__ballot(c & 8))  << 3;
    t += (int)__popcll(__ballot(c & 16)) << 4;
    return t;
}

// == 1 global pass: keys+cmask -> wave-seg append -> 1-wave reg bisect -> cmask write ==
template<bool USE_B>
__global__ __launch_bounds__(TPB, 8)
void kwta_scan(const float* __restrict__ x,
               const float* __restrict__ boost,
               const float* __restrict__ dc,
               float* __restrict__ out,
               int n, int k, unsigned PIV) {
    const int tid  = threadIdx.x;
    const int lane = tid & 63;
    const int wave = tid >> 6;
    const int row  = blockIdx.x;

    __shared__ unsigned s_seg[NWAVE][SEGC];   // wave-private candidate segments
    __shared__ int s_wtot[NWAVE];
    __shared__ int s_cnt[4];
    __shared__ unsigned s_P;

    // ---- pass 1: load row, build 32 keys/thread + candidate mask (no ballots) ----
    const float4* x4 = (const float4*)(x + (size_t)row * n);
    const float4* b4 = (const float4*)boost;
    const float4* d4 = (const float4*)dc;
    unsigned key[KPT];
    #pragma unroll
    for (int i = 0; i < KPT/4; ++i) {
        float4 xv = x4[tid + i * TPB];
        if (USE_B) {
            float4 bv = b4[tid + i * TPB];
            key[4*i+0] = fkey(xv.x * bv.x);
            key[4*i+1] = fkey(xv.y * bv.y);
            key[4*i+2] = fkey(xv.z * bv.z);
            key[4*i+3] = fkey(xv.w * bv.w);
        } else {
            float4 dv = d4[tid + i * TPB];
            key[4*i+0] = fkey(xv.x * (float)exp((double)(1.5f * (0.02f - dv.x))));
            key[4*i+1] = fkey(xv.y * (float)exp((double)(1.5f * (0.02f - dv.y))));
            key[4*i+2] = fkey(xv.z * (float)exp((double)(1.5f * (0.02f - dv.z))));
            key[4*i+3] = fkey(xv.w * (float)exp((double)(1.5f * (0.02f - dv.w))));
        }
    }
    unsigned cmask = 0;
    #pragma unroll
    for (int j = 0; j < KPT; ++j) cmask |= (unsigned)(key[j] >= PIV) << j;
    const int c = __popc(cmask);

    // ---- wave exclusive scan + total via bit-plane ballots (6 ballots, once) ----
    const unsigned long long lt = (1ull << lane) - 1ull;
    int pre = 0, wt = 0;
    #pragma unroll
    for (int b = 0; b < 6; ++b) {
        unsigned long long m = __ballot((c >> b) & 1);
        pre += (int)__popcll(m & lt) << b;
        wt  += (int)__popcll(m) << b;
    }

    // ---- append pass: wave-private segment, scanned offsets, no atomics ----
    {
        int pos = pre;
        unsigned m = cmask;
        while (m) {
            const int j = __ffs(m) - 1;
            m &= m - 1;
            if (pos < SEGC) s_seg[wave][pos] = key[j];
            ++pos;
        }
    }
    if (tid < 4) s_cnt[tid] = 0;              // reset for potential tier-C
    if (lane == 0) s_wtot[wave] = wt;
    __syncthreads();                          // (1) segments + totals visible

    int nc = 0, wmax = 0;
    int cw[NWAVE];
    #pragma unroll
    for (int w = 0; w < NWAVE; ++w) {
        cw[w] = s_wtot[w];
        nc   += cw[w];
        wmax  = (cw[w] > wmax) ? cw[w] : wmax;
    }

    f32x4* o4 = (f32x4*)(out + (size_t)row * n);

    if (nc >= k && nc <= CAPREG && wmax <= SEGC) {
        // ---- tier A: one wave gathers <=16 regs/lane from segments, pure-reg bisect ----
        if (wave == (row & (NWAVE - 1))) {
            unsigned cand[2 * NWAVE];
            #pragma unroll
            for (int w = 0; w < NWAVE; ++w) {
                cand[2*w+0] = (lane      < cw[w]) ? s_seg[w][lane]      : 0u;
                cand[2*w+1] = (lane + 64 < cw[w]) ? s_seg[w][lane + 64] : 0u;
            }
            unsigned Q = 0;
            for (int b = 30; b >= 0; b -= 2) {
                const unsigned CA = Q | (1u << (b + 1));
                const unsigned CB = Q | (1u << b);
                const unsigned CC = CA | (1u << b);
                int ca = 0, cb = 0, cc = 0;
                #pragma unroll
                for (int j = 0; j < 2 * NWAVE; ++j) {
                    ca += (cand[j] >= CA) ? 1 : 0;
                    cb += (cand[j] >= CB) ? 1 : 0;
                    cc += (cand[j] >= CC) ? 1 : 0;
                }
                const int A = wave_sum5(ca);
                const int B = wave_sum5(cb);
                const int C = wave_sum5(cc);
                if (A >= k)      Q = (C >= k) ? CC : CA;
                else if (B >= k) Q = CB;
            }
            if (lane == 0) s_P = Q;
        }
        __syncthreads();                      // (2) P published
        const unsigned P = s_P;

        // ---- write phase: start from cmask, clear losing candidates (LDS re-read,
        // ~1 candidate/thread) — x/boost NOT touched again ----
        unsigned w = cmask;
        {
            int pos = pre;
            unsigned m = cmask;
            while (m) {
                const int j = __ffs(m) - 1;
                m &= m - 1;
                const unsigned v = s_seg[wave][pos];
                ++pos;
                if (v < P) w &= ~(1u << j);
            }
        }
        #pragma unroll
        for (int i = 0; i < KPT/4; ++i) {
            f32x4 o;
            o.x = ((w >> (4*i+0)) & 1u) ? 1.0f : 0.0f;
            o.y = ((w >> (4*i+1)) & 1u) ? 1.0f : 0.0f;
            o.z = ((w >> (4*i+2)) & 1u) ? 1.0f : 0.0f;
            o.w = ((w >> (4*i+3)) & 1u) ? 1.0f : 0.0f;
            __builtin_nontemporal_store(o, &o4[tid + i * TPB]);
        }
    } else {
        // ---- tier C (~never): exact block-wide 32-round bisect over keys ----
        int it = 0;
        unsigned P = 0;
        for (int b = 31; b >= 0; --b) {
            const unsigned C = P | (1u << b);
            int cc = 0;
            #pragma unroll
            for (int j = 0; j < KPT; ++j) cc += (key[j] >= C) ? 1 : 0;
            int t = wave_sum6(cc);
            const int s = it & 3;
            if (lane == 0) atomicAdd(&s_cnt[s], t);
            __syncthreads();
            const int total = s_cnt[s];
            if (tid == 0) s_cnt[(s + 2) & 3] = 0;
            ++it;
            if (total >= k) P = C;
        }
        #pragma unroll
        for (int i = 0; i < KPT/4; ++i) {
            f32x4 o;
            o.x = (key[4*i+0] >= P) ? 1.0f : 0.0f;
            o.y = (key[4*i+1] >= P) ? 1.0f : 0.0f;
            o.z = (key[4*i+2] >= P) ? 1.0f : 0.0f;
            o.w = (key[4*i+3] >= P) ? 1.0f : 0.0f;
            __builtin_nontemporal_store(o, &o4[tid + i * TPB]);
        }
    }
}

extern "C" void kernel_launch(void* const* d_in, const int* in_sizes, int n_in,
                              void* d_out, int out_size, void* d_ws, size_t ws_size,
                              hipStream_t stream) {
    const float* x  = (const float*)d_in[0];
    const float* dc = (const float*)d_in[1];
    float* out = (float*)d_out;

    int n    = in_sizes[1];             // 16384
    int rows = in_sizes[0] / n;         // 4096
    int k    = (int)llround((double)n * 0.02);
    if (k < 1) k = 1;

    // fixed conservative pivot: xb >= 1.15 -> nc ~ 500+-22/row; per-wave counts
    // ~62+-8 (SEGC=128 = +8 sigma); exact tier-C covers any data.
    float pivf = 1.15f;
    unsigned pu;
    memcpy(&pu, &pivf, sizeof(pu));
    unsigned PIV = (pu & 0x80000000u) ? ~pu : (pu | 0x80000000u);

    if (ws_size >= (size_t)n * sizeof(float)) {
        float* boost = (float*)d_ws;
        boost_kernel<<<(n + 255) / 256, 256, 0, stream>>>(dc, boost, n);
        kwta_scan<true><<<rows, TPB, 0, stream>>>(x, boost, dc, out, n, k, PIV);
    } else {
        kwta_scan<false><<<rows, TPB, 0, stream>>>(x, nullptr, dc, out, n, k, PIV);
    }
}

// Round 20
// 129.659 us; speedup vs baseline: 1.2783x; 1.2783x over previous
//
#include <hip/hip_runtime.h>
#include <math.h>
#include <string.h>

#define TPB    512        // threads per block (8 waves)
#define KPT    32         // keys per thread; n = TPB*KPT = 16384
#define SEGC   128        // per-wave segment capacity (8*128*4B = 4 KiB LDS)
#define CAPREG 1024       // tier-A cap: 16 regs/lane * 64 lanes
#define NWAVE  (TPB/64)

typedef float f32x4 __attribute__((ext_vector_type(4)));   // native vec for NT store

// LDS-only barrier: does NOT drain vmcnt (global stores stay in flight).
__device__ __forceinline__ void lds_barrier() {
    __builtin_amdgcn_sched_barrier(0);
    asm volatile("s_waitcnt lgkmcnt(0)" ::: "memory");
    __builtin_amdgcn_s_barrier();
    __builtin_amdgcn_sched_barrier(0);
}

// ---------------- boost precompute: boost = f32(exp(f64(1.5f*(0.02f - dc)))) ----
__global__ void boost_kernel(const float* __restrict__ dc, float* __restrict__ boost, int n) {
    int i = blockIdx.x * blockDim.x + threadIdx.x;
    if (i < n) {
        float a = 1.5f * (0.02f - dc[i]);   // exact f32 arithmetic, same as reference
        boost[i] = (float)exp((double)a);   // correctly-rounded f32 exp via f64
    }
}

// monotone float -> uint32 key (no NaNs in input)
__device__ __forceinline__ unsigned fkey(float f) {
    unsigned u = __float_as_uint(f);
    return (u & 0x80000000u) ? ~u : (u | 0x80000000u);
}

// wave-wide sums of per-lane counts via bit-plane ballots; uniform result.
__device__ __forceinline__ int wave_sum6(int c) {
    int t;
    t  = (int)__popcll(__ballot(c & 1));
    t += (int)__popcll(__ballot(c & 2))  << 1;
    t += (int)__popcll(__ballot(c & 4))  << 2;
    t += (int)__popcll(__ballot(c & 8))  << 3;
    t += (int)__popcll(__ballot(c & 16)) << 4;
    t += (int)__popcll(__ballot(c & 32)) << 5;
    return t;
}
__device__ __forceinline__ int wave_sum5(int c) {   // counts <= 16 per lane
    int t;
    t  = (int)__popcll(__ballot(c & 1));
    t += (int)__popcll(__ballot(c & 2))  << 1;
    t += (int)__popcll(__ballot(c & 4))  << 2;
    t += (int)__popcll(__ballot(c & 8))  << 3;
    t += (int)__popcll(__ballot(c & 16)) << 4;
    return t;
}

// == scan-compact -> dense PIV write ∥ 1-wave reg bisect -> owner fixup of losers ==
template<bool USE_B>
__global__ __launch_bounds__(TPB, 8)
void kwta_scan(const float* __restrict__ x,
               const float* __restrict__ boost,
               const float* __restrict__ dc,
               float* __restrict__ out,
               int n, int k, unsigned PIV) {
    const int tid  = threadIdx.x;
    const int lane = tid & 63;
    const int wave = tid >> 6;
    const int row  = blockIdx.x;

    __shared__ unsigned s_seg[NWAVE][SEGC];   // wave-private candidate segments
    __shared__ int s_wtot[NWAVE];
    __shared__ int s_cnt[4];
    __shared__ unsigned s_P;

    // ---- load row, build 32 keys/thread in registers (static indexing only) ----
    const float4* x4 = (const float4*)(x + (size_t)row * n);
    const float4* b4 = (const float4*)boost;
    const float4* d4 = (const float4*)dc;
    unsigned key[KPT];
    #pragma unroll
    for (int i = 0; i < KPT/4; ++i) {
        float4 xv = x4[tid + i * TPB];
        if (USE_B) {
            float4 bv = b4[tid + i * TPB];
            key[4*i+0] = fkey(xv.x * bv.x);
            key[4*i+1] = fkey(xv.y * bv.y);
            key[4*i+2] = fkey(xv.z * bv.z);
            key[4*i+3] = fkey(xv.w * bv.w);
        } else {
            float4 dv = d4[tid + i * TPB];
            key[4*i+0] = fkey(xv.x * (float)exp((double)(1.5f * (0.02f - dv.x))));
            key[4*i+1] = fkey(xv.y * (float)exp((double)(1.5f * (0.02f - dv.y))));
            key[4*i+2] = fkey(xv.z * (float)exp((double)(1.5f * (0.02f - dv.z))));
            key[4*i+3] = fkey(xv.w * (float)exp((double)(1.5f * (0.02f - dv.w))));
        }
    }

    // ---- candidate mask + count ----
    unsigned cmask = 0;
    #pragma unroll
    for (int j = 0; j < KPT; ++j) cmask |= (unsigned)(key[j] >= PIV) << j;
    const int c = __popc(cmask);

    // ---- wave exclusive scan + total via bit-plane ballots ----
    const unsigned long long lt = (1ull << lane) - 1ull;
    int pre = 0, wt = 0;
    #pragma unroll
    for (int b = 0; b < 6; ++b) {
        unsigned long long m = __ballot((c >> b) & 1);
        pre += (int)__popcll(m & lt) << b;
        wt  += (int)__popcll(m) << b;
    }

    // ---- append to wave-private segment (STATIC j loop; no dynamic reg index) ----
    {
        int pos = pre;
        #pragma unroll
        for (int j = 0; j < KPT; ++j) {
            if (key[j] >= PIV) {
                if (pos < SEGC) s_seg[wave][pos] = key[j];
                ++pos;
            }
        }
    }
    if (tid < 4) s_cnt[tid] = 0;              // reset for potential tier-C
    if (lane == 0) s_wtot[wave] = wt;
    __syncthreads();                          // (1) segments + totals visible

    int nc = 0, wmax = 0;
    int cw[NWAVE];
    #pragma unroll
    for (int w = 0; w < NWAVE; ++w) {
        cw[w] = s_wtot[w];
        nc   += cw[w];
        wmax  = (cw[w] > wmax) ? cw[w] : wmax;
    }

    f32x4* o4 = (f32x4*)(out + (size_t)row * n);

    if (nc >= k && nc <= CAPREG && wmax <= SEGC) {
        // ---- ALL waves: dense NT write with PIV now (correct except losing
        // candidates). Keys die here; stores retire during the bisect. ----
        #pragma unroll
        for (int i = 0; i < KPT/4; ++i) {
            f32x4 o;
            o.x = (key[4*i+0] >= PIV) ? 1.0f : 0.0f;
            o.y = (key[4*i+1] >= PIV) ? 1.0f : 0.0f;
            o.z = (key[4*i+2] >= PIV) ? 1.0f : 0.0f;
            o.w = (key[4*i+3] >= PIV) ? 1.0f : 0.0f;
            __builtin_nontemporal_store(o, &o4[tid + i * TPB]);
        }

        // ---- one wave: gather <=16 regs/lane from segments, pure-register bisect ----
        if (wave == (row & (NWAVE - 1))) {
            unsigned cand[2 * NWAVE];
            #pragma unroll
            for (int w = 0; w < NWAVE; ++w) {
                cand[2*w+0] = (lane      < cw[w]) ? s_seg[w][lane]      : 0u;
                cand[2*w+1] = (lane + 64 < cw[w]) ? s_seg[w][lane + 64] : 0u;
            }
            unsigned Q = 0;
            for (int b = 30; b >= 0; b -= 2) {
                const unsigned CA = Q | (1u << (b + 1));
                const unsigned CB = Q | (1u << b);
                const unsigned CC = CA | (1u << b);
                int ca = 0, cb = 0, cc = 0;
                #pragma unroll
                for (int j = 0; j < 2 * NWAVE; ++j) {
                    ca += (cand[j] >= CA) ? 1 : 0;
                    cb += (cand[j] >= CB) ? 1 : 0;
                    cc += (cand[j] >= CC) ? 1 : 0;
                }
                const int A = wave_sum5(ca);
                const int B = wave_sum5(cb);
                const int C = wave_sum5(cc);
                if (A >= k)      Q = (C >= k) ? CC : CA;
                else if (B >= k) Q = CB;
            }
            if (lane == 0) s_P = Q;
        }
        lds_barrier();                        // (2) P published; stores keep flying
        const unsigned P = s_P;

        // ---- owner fixup: drain OWN stores (retired during bisect), then zero
        // losing candidates. Columns from cmask bits; values from own LDS slots. ----
        asm volatile("s_waitcnt vmcnt(0)" ::: "memory");
        if (P > PIV) {                        // P == PIV -> no losers
            int pos = pre;
            unsigned m = cmask;
            while (m) {
                const int j = __ffs(m) - 1;   // m is unsigned int
                m &= m - 1;
                const unsigned v = s_seg[wave][pos];
                ++pos;
                if (v < P) {
                    const int col = 4 * (tid + (j >> 2) * TPB) + (j & 3);
                    out[(size_t)row * n + col] = 0.0f;
                }
            }
        }
    } else {
        // ---- tier C (~never): exact block-wide bisect; first __syncthreads inside
        // the loop drains any in-flight stores; dense rewrite with exact P. ----
        int it = 0;
        unsigned P = 0;
        for (int b = 31; b >= 0; --b) {
            const unsigned C = P | (1u << b);
            int cc2 = 0;
            #pragma unroll
            for (int j = 0; j < KPT; ++j) cc2 += (key[j] >= C) ? 1 : 0;
            int t = wave_sum6(cc2);
            const int s = it & 3;
            if (lane == 0) atomicAdd(&s_cnt[s], t);
            __syncthreads();
            const int total = s_cnt[s];
            if (tid == 0) s_cnt[(s + 2) & 3] = 0;
            ++it;
            if (total >= k) P = C;
        }
        #pragma unroll
        for (int i = 0; i < KPT/4; ++i) {
            f32x4 o;
            o.x = (key[4*i+0] >= P) ? 1.0f : 0.0f;
            o.y = (key[4*i+1] >= P) ? 1.0f : 0.0f;
            o.z = (key[4*i+2] >= P) ? 1.0f : 0.0f;
            o.w = (key[4*i+3] >= P) ? 1.0f : 0.0f;
            __builtin_nontemporal_store(o, &o4[tid + i * TPB]);
        }
    }
}

extern "C" void kernel_launch(void* const* d_in, const int* in_sizes, int n_in,
                              void* d_out, int out_size, void* d_ws, size_t ws_size,
                              hipStream_t stream) {
    const float* x  = (const float*)d_in[0];
    const float* dc = (const float*)d_in[1];
    float* out = (float*)d_out;

    int n    = in_sizes[1];             // 16384
    int rows = in_sizes[0] / n;         // 4096
    int k    = (int)llround((double)n * 0.02);
    if (k < 1) k = 1;

    // fixed conservative pivot: xb >= 1.15 -> nc ~ 500+-22/row; per-wave counts
    // ~62+-8 (SEGC=128 = +8 sigma); exact tier-C covers any data.
    float pivf = 1.15f;
    unsigned pu;
    memcpy(&pu, &pivf, sizeof(pu));
    unsigned PIV = (pu & 0x80000000u) ? ~pu : (pu | 0x80000000u);

    if (ws_size >= (size_t)n * sizeof(float)) {
        float* boost = (float*)d_ws;
        boost_kernel<<<(n + 255) / 256, 256, 0, stream>>>(dc, boost, n);
        kwta_scan<true><<<rows, TPB, 0, stream>>>(x, boost, dc, out, n, k, PIV);
    } else {
        kwta_scan<false><<<rows, TPB, 0, stream>>>(x, nullptr, dc, out, n, k, PIV);
    }
}

// Round 21
// 95.231 us; speedup vs baseline: 1.7404x; 1.3615x over previous
//
#include <hip/hip_runtime.h>
#include <math.h>
#include <string.h>

#define TPB    512        // threads per block (8 waves)
#define KPT    32         // keys per thread; n = TPB*KPT = 16384
#define CAP    2048       // candidate list capacity (8 KiB LDS)
#define CAPREG 512        // tier-A cap: 8 regs/lane * 64 lanes
#define NWAVE  (TPB/64)

typedef float f32x4 __attribute__((ext_vector_type(4)));   // native vec for NT store

// ---------------- boost precompute: boost = f32(exp(f64(1.5f*(0.02f - dc)))) ----
__global__ void boost_kernel(const float* __restrict__ dc, float* __restrict__ boost, int n) {
    int i = blockIdx.x * blockDim.x + threadIdx.x;
    if (i < n) {
        float a = 1.5f * (0.02f - dc[i]);   // exact f32 arithmetic, same as reference
        boost[i] = (float)exp((double)a);   // correctly-rounded f32 exp via f64
    }
}

// monotone float -> uint32 key (no NaNs in input)
__device__ __forceinline__ unsigned fkey(float f) {
    unsigned u = __float_as_uint(f);
    return (u & 0x80000000u) ? ~u : (u | 0x80000000u);
}

// wave-wide sum of per-lane count c (0..63) via bit-plane ballots; uniform result.
__device__ __forceinline__ int wave_sum6(int c) {
    int t;
    t  = (int)__popcll(__ballot(c & 1));
    t += (int)__popcll(__ballot(c & 2))  << 1;
    t += (int)__popcll(__ballot(c & 4))  << 2;
    t += (int)__popcll(__ballot(c & 8))  << 3;
    t += (int)__popcll(__ballot(c & 16)) << 4;
    t += (int)__popcll(__ballot(c & 32)) << 5;
    return t;
}
__device__ __forceinline__ int wave_sum4(int c) {   // counts <= 8 per lane
    int t;
    t  = (int)__popcll(__ballot(c & 1));
    t += (int)__popcll(__ballot(c & 2)) << 1;
    t += (int)__popcll(__ballot(c & 4)) << 2;
    t += (int)__popcll(__ballot(c & 8)) << 3;
    return t;
}

// ======== one-pass: reg-resident keys -> scan-compact -> 1-wave bisect -> write ====
// launch_bounds(.,6): 85-VGPR budget lets key[32] stay register-resident (no L2
// remat passes); measured occupancy was ~70% anyway, so no occupancy loss.
template<bool USE_B>
__global__ __launch_bounds__(TPB, 6)
void kwta_scan(const float* __restrict__ x,
               const float* __restrict__ boost,
               const float* __restrict__ dc,
               float* __restrict__ out,
               int n, int k, unsigned PIV) {
    const int tid  = threadIdx.x;
    const int lane = tid & 63;
    const int wave = tid >> 6;
    const int row  = blockIdx.x;

    __shared__ unsigned s_key[CAP];
    __shared__ int s_wtot[NWAVE];
    __shared__ int s_cnt[4];
    __shared__ unsigned s_P;

    // ---- load row, build 32 keys/thread in registers ----
    const float4* x4 = (const float4*)(x + (size_t)row * n);
    const float4* b4 = (const float4*)boost;
    const float4* d4 = (const float4*)dc;
    unsigned key[KPT];
    #pragma unroll
    for (int i = 0; i < KPT/4; ++i) {
        float4 xv = x4[tid + i * TPB];
        if (USE_B) {
            float4 bv = b4[tid + i * TPB];
            key[4*i+0] = fkey(xv.x * bv.x);
            key[4*i+1] = fkey(xv.y * bv.y);
            key[4*i+2] = fkey(xv.z * bv.z);
            key[4*i+3] = fkey(xv.w * bv.w);
        } else {
            float4 dv = d4[tid + i * TPB];
            key[4*i+0] = fkey(xv.x * (float)exp((double)(1.5f * (0.02f - dv.x))));
            key[4*i+1] = fkey(xv.y * (float)exp((double)(1.5f * (0.02f - dv.y))));
            key[4*i+2] = fkey(xv.z * (float)exp((double)(1.5f * (0.02f - dv.z))));
            key[4*i+3] = fkey(xv.w * (float)exp((double)(1.5f * (0.02f - dv.w))));
        }
    }

    // ---- per-thread candidate count ----
    int c = 0;
    #pragma unroll
    for (int j = 0; j < KPT; ++j) c += (key[j] >= PIV) ? 1 : 0;

    // ---- wave-level exclusive scan + total via bit-plane ballots (no chain) ----
    const unsigned long long lt = (1ull << lane) - 1ull;
    int pre = 0, wt = 0;
    #pragma unroll
    for (int b = 0; b < 6; ++b) {
        unsigned long long m = __ballot((c >> b) & 1);
        pre += (int)__popcll(m & lt) << b;
        wt  += (int)__popcll(m) << b;
    }
    if (tid < 4) s_cnt[tid] = 0;         // reset for potential fallback
    if (lane == 0) s_wtot[wave] = wt;
    __syncthreads();                     // (1) wave totals visible

    int base = 0, nc = 0;
    #pragma unroll
    for (int w = 0; w < NWAVE; ++w) {
        const int t = s_wtot[w];
        base += (w < wave) ? t : 0;
        nc   += t;
    }
    int off = base + pre;

    // ---- append candidates at scanned offsets (atomic-free) ----
    #pragma unroll
    for (int j = 0; j < KPT; ++j) {
        if (key[j] >= PIV) {
            if (off < CAP) s_key[off] = key[j];
            ++off;
        }
    }
    __syncthreads();                     // (2) candidate list ready

    unsigned P;
    if (nc >= k && nc <= CAPREG) {
        // ---- tier A: one wave, candidates cached in 8 regs, pure-register rounds ----
        if (wave == (row & (NWAVE - 1))) {
            unsigned cand[8];
            #pragma unroll
            for (int j = 0; j < 8; ++j) {
                const int idx = lane + (j << 6);
                cand[j] = (idx < nc) ? s_key[idx] : 0u;   // 0 never >= probe
            }
            unsigned Q = 0;
            for (int b = 30; b >= 0; b -= 2) {
                const unsigned CA = Q | (1u << (b + 1));
                const unsigned CB = Q | (1u << b);
                const unsigned CC = CA | (1u << b);
                int ca = 0, cb = 0, cc = 0;
                #pragma unroll
                for (int j = 0; j < 8; ++j) {
                    ca += (cand[j] >= CA) ? 1 : 0;
                    cb += (cand[j] >= CB) ? 1 : 0;
                    cc += (cand[j] >= CC) ? 1 : 0;
                }
                const int A = wave_sum4(ca);
                const int B = wave_sum4(cb);
                const int C = wave_sum4(cc);
                if (A >= k)      Q = (C >= k) ? CC : CA;
                else if (B >= k) Q = CB;
            }
            if (lane == 0) s_P = Q;
        }
        __syncthreads();                 // (3) P published
        P = s_P;
    } else if (nc >= k && nc <= CAP) {
        // ---- tier B: single-wave LDS-read bisect (nc in (512, 2048]) ----
        if (wave == (row & (NWAVE - 1))) {
            const int mrd = (nc + 63) >> 6;
            unsigned Q = 0;
            for (int b = 30; b >= 0; b -= 2) {
                const unsigned CA = Q | (1u << (b + 1));
                const unsigned CB = Q | (1u << b);
                const unsigned CC = CA | (1u << b);
                int ca = 0, cb = 0, cc = 0;
                for (int j = 0; j < mrd; ++j) {
                    const int idx = lane + (j << 6);
                    const unsigned v = (idx < nc) ? s_key[idx] : 0u;  // 0 never >= probe
                    ca += (v >= CA) ? 1 : 0;
                    cb += (v >= CB) ? 1 : 0;
                    cc += (v >= CC) ? 1 : 0;
                }
                const int A = wave_sum6(ca);
                const int B = wave_sum6(cb);
                const int C = wave_sum6(cc);
                if (A >= k)      Q = (C >= k) ? CC : CA;
                else if (B >= k) Q = CB;
            }
            if (lane == 0) s_P = Q;
        }
        __syncthreads();                 // (3) P published
        P = s_P;
    } else {
        // ---- tier C (~never): block-wide 32-round bisect over register keys ----
        int it = 0;
        P = 0;
        for (int b = 31; b >= 0; --b) {
            const unsigned C = P | (1u << b);
            int cc = 0;
            #pragma unroll
            for (int j = 0; j < KPT; ++j) cc += (key[j] >= C) ? 1 : 0;
            int t = wave_sum6(cc);
            const int s = it & 3;
            if (lane == 0) atomicAdd(&s_cnt[s], t);
            __syncthreads();
            const int total = s_cnt[s];
            if (tid == 0) s_cnt[(s + 2) & 3] = 0;
            ++it;
            if (total >= k) P = C;
        }
    }

    // ---- dense write straight from registers; nontemporal float4 stream ----
    f32x4* o4 = (f32x4*)(out + (size_t)row * n);
    #pragma unroll
    for (int i = 0; i < KPT/4; ++i) {
        f32x4 o;
        o.x = (key[4*i+0] >= P) ? 1.0f : 0.0f;
        o.y = (key[4*i+1] >= P) ? 1.0f : 0.0f;
        o.z = (key[4*i+2] >= P) ? 1.0f : 0.0f;
        o.w = (key[4*i+3] >= P) ? 1.0f : 0.0f;
        __builtin_nontemporal_store(o, &o4[tid + i * TPB]);
    }
}

extern "C" void kernel_launch(void* const* d_in, const int* in_sizes, int n_in,
                              void* d_out, int out_size, void* d_ws, size_t ws_size,
                              hipStream_t stream) {
    const float* x  = (const float*)d_in[0];
    const float* dc = (const float*)d_in[1];
    float* out = (float*)d_out;

    int n    = in_sizes[1];             // 16384
    int rows = in_sizes[0] / n;         // 4096
    int k    = (int)llround((double)n * 0.02);
    if (k < 1) k = 1;

    // fixed conservative pivot: xb >= 1.15 -> nc ~ 500+-22/row (tier-A reg cap 512,
    // tier-B LDS cap 2048); exact tier-C covers any data.
    float pivf = 1.15f;
    unsigned pu;
    memcpy(&pu, &pivf, sizeof(pu));
    unsigned PIV = (pu & 0x80000000u) ? ~pu : (pu | 0x80000000u);

    if (ws_size >= (size_t)n * sizeof(float)) {
        float* boost = (float*)d_ws;
        boost_kernel<<<(n + 255) / 256, 256, 0, stream>>>(dc, boost, n);
        kwta_scan<true><<<rows, TPB, 0, stream>>>(x, boost, dc, out, n, k, PIV);
    } else {
        kwta_scan<false><<<rows, TPB, 0, stream>>>(x, nullptr, dc, out, n, k, PIV);
    }
}